// Round 1
// baseline (84.854 us; speedup 1.0000x reference)
//
#include <hip/hip_runtime.h>

#define B_SIZE 4
#define D_MODEL 1024
#define SEQ_L 2048
#define N_STATE 64
#define TILE_T 64
#define ROWS 256
#define PADS 65  // padded LDS row stride (floats): bank = (r + t) % 32 -> conflict-free

// ---------------- pass 1: chunk-local final states (zero init) ----------------
__global__ __launch_bounds__(256, 2) void ssm_pass1(const float* __restrict__ u,
                                                    const float* __restrict__ A,
                                                    float* __restrict__ s,
                                                    int C, int Tc) {
    __shared__ float tile[ROWS * PADS];
    const int bx  = blockIdx.x;
    const int c   = bx % C;
    const int rem = bx / C;
    const int b   = rem % B_SIZE;
    const int d0  = (rem / B_SIZE) * ROWS;
    const int tid  = threadIdx.x;
    const int wid  = tid >> 6;
    const int lane = tid & 63;

    float a[N_STATE];
#pragma unroll
    for (int i = 0; i < N_STATE; ++i) a[i] = A[i * (N_STATE + 1)];

    float g[N_STATE];
#pragma unroll
    for (int i = 0; i < N_STATE; ++i) g[i] = 0.f;

    const int t0 = c * Tc;
    const int nt = Tc / TILE_T;
    for (int tt = 0; tt < nt; ++tt) {
        const int tbase = t0 + tt * TILE_T;
        for (int r = wid; r < ROWS; r += 4) {
            tile[r * PADS + lane] = u[(size_t)(b * D_MODEL + d0 + r) * SEQ_L + tbase + lane];
        }
        __syncthreads();
        const float* row = &tile[tid * PADS];
#pragma unroll 2
        for (int t = 0; t < TILE_T; ++t) {
            const float uv = row[t];
#pragma unroll
            for (int i = 0; i < N_STATE; ++i) g[i] = fmaf(a[i], g[i], uv);
        }
        __syncthreads();
    }

    const int d = d0 + tid;
#pragma unroll
    for (int i = 0; i < N_STATE; ++i)
        s[(((size_t)c * B_SIZE + b) * N_STATE + i) * D_MODEL + d] = g[i];
}

// ---------------- combine: local end-states -> true chunk-initial states (in place) ----------------
__global__ void ssm_combine(const float* __restrict__ A, float* __restrict__ s,
                            int C, int Tc) {
    const int tid = blockIdx.x * blockDim.x + threadIdx.x;  // B*N*D threads
    const int d   = tid & (D_MODEL - 1);
    const int rem = tid >> 10;
    const int i   = rem & (N_STATE - 1);
    const int b   = rem >> 6;

    const float a = A[i * (N_STATE + 1)];
    // aT = a^Tc, Tc is a power of two
    int k = 0;
    for (int v = Tc; v > 1; v >>= 1) ++k;
    float aT = a;
    for (int j = 0; j < k; ++j) aT = aT * aT;

    float run = 0.f;
    for (int c = 0; c < C; ++c) {
        const size_t idx = (((size_t)c * B_SIZE + b) * N_STATE + i) * D_MODEL + d;
        const float sl = s[idx];
        s[idx] = run;                 // true initial state of chunk c
        run = fmaf(aT, run, sl);
    }
}

// ---------------- pass 2: full recurrence with correct init, produce y ----------------
__global__ __launch_bounds__(256, 2) void ssm_pass2(const float* __restrict__ u,
                                                    const float* __restrict__ A,
                                                    const float* __restrict__ Bv,
                                                    const float* __restrict__ Cv,
                                                    const float* __restrict__ s,
                                                    float* __restrict__ y,
                                                    int C, int Tc) {
    __shared__ float tile[ROWS * PADS];
    const int bx  = blockIdx.x;
    const int c   = bx % C;
    const int rem = bx / C;
    const int b   = rem % B_SIZE;
    const int d0  = (rem / B_SIZE) * ROWS;
    const int tid  = threadIdx.x;
    const int wid  = tid >> 6;
    const int lane = tid & 63;

    float a[N_STATE], w[N_STATE];
#pragma unroll
    for (int i = 0; i < N_STATE; ++i) {
        a[i] = A[i * (N_STATE + 1)];
        w[i] = Bv[i] * Cv[i];
    }

    float g[N_STATE];
    const int d = d0 + tid;
    if (C > 1) {
#pragma unroll
        for (int i = 0; i < N_STATE; ++i)
            g[i] = s[(((size_t)c * B_SIZE + b) * N_STATE + i) * D_MODEL + d];
    } else {
#pragma unroll
        for (int i = 0; i < N_STATE; ++i) g[i] = 0.f;
    }

    const int t0 = c * Tc;
    const int nt = Tc / TILE_T;
    for (int tt = 0; tt < nt; ++tt) {
        const int tbase = t0 + tt * TILE_T;
        for (int r = wid; r < ROWS; r += 4) {
            tile[r * PADS + lane] = u[(size_t)(b * D_MODEL + d0 + r) * SEQ_L + tbase + lane];
        }
        __syncthreads();
        float* row = &tile[tid * PADS];
#pragma unroll 2
        for (int t = 0; t < TILE_T; ++t) {
            const float uv = row[t];
            float y0 = 0.f, y1 = 0.f, y2 = 0.f, y3 = 0.f;
#pragma unroll
            for (int i = 0; i < N_STATE; i += 4) {
                g[i + 0] = fmaf(a[i + 0], g[i + 0], uv); y0 = fmaf(w[i + 0], g[i + 0], y0);
                g[i + 1] = fmaf(a[i + 1], g[i + 1], uv); y1 = fmaf(w[i + 1], g[i + 1], y1);
                g[i + 2] = fmaf(a[i + 2], g[i + 2], uv); y2 = fmaf(w[i + 2], g[i + 2], y2);
                g[i + 3] = fmaf(a[i + 3], g[i + 3], uv); y3 = fmaf(w[i + 3], g[i + 3], y3);
            }
            row[t] = (y0 + y1) + (y2 + y3);   // overwrite consumed u slot with y
        }
        __syncthreads();
        for (int r = wid; r < ROWS; r += 4) {
            y[(size_t)(b * D_MODEL + d0 + r) * SEQ_L + tbase + lane] = tile[r * PADS + lane];
        }
        __syncthreads();
    }
}

extern "C" void kernel_launch(void* const* d_in, const int* in_sizes, int n_in,
                              void* d_out, int out_size, void* d_ws, size_t ws_size,
                              hipStream_t stream) {
    const float* u  = (const float*)d_in[0];
    const float* A  = (const float*)d_in[1];
    const float* Bv = (const float*)d_in[2];
    const float* Cv = (const float*)d_in[3];
    float* y = (float*)d_out;
    float* s = (float*)d_ws;

    // choose chunk count by available workspace (C MB needed); power of two
    int C = 32;
    while (C > 1 && (size_t)C * B_SIZE * N_STATE * D_MODEL * sizeof(float) > ws_size) C >>= 1;
    const int Tc = SEQ_L / C;

    const int nblocks = C * B_SIZE * (D_MODEL / ROWS);
    if (C > 1) {
        ssm_pass1<<<nblocks, 256, 0, stream>>>(u, A, s, C, Tc);
        ssm_combine<<<(B_SIZE * N_STATE * D_MODEL) / 256, 256, 0, stream>>>(A, s, C, Tc);
    }
    ssm_pass2<<<nblocks, 256, 0, stream>>>(u, A, Bv, Cv, s, y, C, Tc);
}